// Round 14
// baseline (943.413 us; speedup 1.0000x reference)
//
#include <hip/hip_runtime.h>
#include <hip/hip_bf16.h>

#define Vn 25000
#define En 100000
#define NODE_IN 74
#define EDGE_IN 12
#define OUTD 64
#define EHID 128
#define NUM_STEPS 6

typedef __attribute__((ext_vector_type(8))) _Float16 half8;
typedef __attribute__((ext_vector_type(2))) _Float16 half2v;
typedef __attribute__((ext_vector_type(4))) float floatx4;

// h[v,o] = relu(node[v,:] @ Wp + bp)   [V,74]@[74,64]  (all fp32)
__global__ void proj_kernel(const float* __restrict__ node,
                            const float* __restrict__ Wp,
                            const float* __restrict__ bp,
                            float* __restrict__ h) {
  __shared__ float nf[NODE_IN];
  int v = blockIdx.x;
  int o = threadIdx.x;  // 64
  for (int i = o; i < NODE_IN; i += 64) nf[i] = node[(size_t)v * NODE_IN + i];
  __syncthreads();
  float acc = bp[o];
  for (int i = 0; i < NODE_IN; ++i) acc = fmaf(nf[i], Wp[i * OUTD + o], acc);
  h[(size_t)v * OUTD + o] = fmaxf(acc, 0.0f);
}

// f[e,k] = relu(edge[e,:] @ We1 + be1)   [E,12]@[12,128] fp32, stored f16
__global__ void edge_kernel(const float* __restrict__ ef,
                            const float* __restrict__ We1,
                            const float* __restrict__ be1,
                            _Float16* __restrict__ f) {
  __shared__ float es[EDGE_IN];
  int e = blockIdx.x;
  int k = threadIdx.x;  // 128
  if (k < EDGE_IN) es[k] = ef[(size_t)e * EDGE_IN + k];
  __syncthreads();
  float acc = be1[k];
  for (int j = 0; j < EDGE_IN; ++j) acc = fmaf(es[j], We1[j * EHID + k], acc);
  f[(size_t)e * EHID + k] = (_Float16)fmaxf(acc, 0.0f);
}

// SSTEP-contiguous + bank-swizzled B layout (f16) — unchanged from r7.
// Logical index: g = step*2048 + c*512 + l15*32 + quad*8 + j, step = i*4+s,
// value = f16(We2[k = s*32+quad*8+j][col = i*64 + c*16 + l15]).
// Stored at step*2048 + (eidx ^ ((eidx>>6 & 3) << 3))  (quad ^= l15[2:1]).
__global__ void w2r_kernel(const float* __restrict__ We2,
                           _Float16* __restrict__ w2s) {
  int g = blockIdx.x * 256 + threadIdx.x;  // < 524288 (logical index)
  int j = g & 7;
  int quad = (g >> 3) & 3;
  int l15 = (g >> 5) & 15;
  int c = (g >> 9) & 3;
  int step = g >> 11;     // 0..255
  int s = step & 3;
  int i = step >> 2;
  int k = s * 32 + quad * 8 + j;
  int col = i * 64 + c * 16 + l15;
  int eidx = g & 2047;
  int estore = eidx ^ (((eidx >> 6) & 3) << 3);
  w2s[((size_t)step << 11) | estore] = (_Float16)We2[(size_t)k * (OUTD * OUTD) + col];
}

#define GLOAD_LDS(gp, lp)                                                     \
  __builtin_amdgcn_global_load_lds(                                           \
      (const __attribute__((address_space(1))) void*)(gp),                    \
      (__attribute__((address_space(3))) void*)(lp), 16, 0, 0)

// Fused per-step message kernel: shared 8-slot B ring, 2-STEP GROUPS.
// Block = 128 edges; wave wv owns edges [32wv,32wv+32) over the FULL K.
// All waves traverse the same 256-step B sequence; wave wv stages only
// stripe wv. Group g (steps n=2g, n+1):
//   vmcnt(2)  (own stages of group g-2 retired -> steps n+2,n+3 landed)
//   s_barrier (all waves' stripes landed; all reads of the slots about to
//              be staged were MFMA-consumed in group g-1 -> retired)
//   read B(n+2),B(n+3) -> V-pair   (consumed NEXT group)
//   stage steps n+6,n+7 -> slots (n+6)&7,(n+7)&7  (3-group lead)
//   sched_barrier(0)   (pin reads/stages early; rule-#18 hygiene)
//   32 MFMAs on U-pair = B(n),B(n+1), in registers since last group
// vs r12/r13: HALF the barriers (128), 2x the MFMA cluster (310 cyc), and
// no ds-latency in the MFMA critical path.
__global__ __launch_bounds__(256, 3) void msg_kernel(
    const float* __restrict__ h,
    const _Float16* __restrict__ f,
    const _Float16* __restrict__ w2s,
    const int* __restrict__ src,
    const int* __restrict__ dst,
    const float* __restrict__ be2,
    float* __restrict__ agg) {
  // [0,16384): per-wave h16 regions (4KB each): [64 i][32 pe] f16,
  //            pe(e) = (e&15)*2 + (e>>4)  -> reader's (t=0,1) pair is one b32.
  // [16384,49152): shared 8-slot B ring (4KB slots).
  __shared__ __align__(16) char smem_raw[49152];
  __shared__ int s_dst[128];

  const int tid = threadIdx.x;
  const int wv = tid >> 6;
  const int lane = tid & 63;
  const int quad = lane >> 4;
  const int l15 = lane & 15;
  const int e0 = blockIdx.x * 128;
  const int ew0 = e0 + wv * 32;   // this wave's first edge

  _Float16* h16w = (_Float16*)(smem_raw + wv * 4096);
  char* ring = smem_raw + 16384;

  // dst (wave-local 32 entries)
  if (lane < 32) {
    int eg = ew0 + lane;
    s_dst[wv * 32 + lane] = (eg < En) ? dst[eg] : -1;
  }
  // h gather (wave-private): lane l -> edge e_local = l&31, i-half = l>>5
  {
    int el = lane & 31;
    int ih = lane >> 5;
    int eg = ew0 + el;
    int sv = (eg < En) ? src[eg] : 0;
    const float4* hp = reinterpret_cast<const float4*>(h + (size_t)sv * OUTD + ih * 32);
    int pe = (el & 15) * 2 + (el >> 4);
#pragma unroll
    for (int c = 0; c < 8; ++c) {
      float4 v = hp[c];
      int i4 = ih * 32 + c * 4;
      h16w[(i4 + 0) * 32 + pe] = (_Float16)v.x;
      h16w[(i4 + 1) * 32 + pe] = (_Float16)v.y;
      h16w[(i4 + 2) * 32 + pe] = (_Float16)v.z;
      h16w[(i4 + 3) * 32 + pe] = (_Float16)v.w;
    }
  }

  // A-fragments: F rows for this wave's 2 row-tiles x 4 K-steps.
  half8 afr[2][4];
#pragma unroll
  for (int t = 0; t < 2; ++t) {
    int e = ew0 + t * 16 + l15;
    if (e >= En) e = En - 1;  // clamped rows suppressed at scatter
    const _Float16* fr = f + (size_t)e * EHID + quad * 8;
#pragma unroll
    for (int s = 0; s < 4; ++s)
      afr[t][s] = *reinterpret_cast<const half8*>(fr + s * 32);
  }

  floatx4 acc[2][4];  // [row-tile t][col-stripe c] — full K sum (AGPRs)
  const floatx4 zero4 = (floatx4){0.f, 0.f, 0.f, 0.f};
#pragma unroll
  for (int t = 0; t < 2; ++t)
#pragma unroll
    for (int c = 0; c < 4; ++c) acc[t][c] = zero4;

  const char* w2b = (const char*)w2s;
  // swizzled per-lane byte offset within a 4KB chunk (stripe c adds 1024)
  const int roff = l15 * 64 + ((quad ^ ((l15 >> 1) & 3)) << 4);
  const char* sp0 = ring + roff;
  const char* sp1 = ring + 4096 + roff;
  const char* sp2 = ring + 8192 + roff;
  const char* sp3 = ring + 12288 + roff;
  const char* sp4 = ring + 16384 + roff;
  const char* sp5 = ring + 20480 + roff;
  const char* sp6 = ring + 24576 + roff;
  const char* sp7 = ring + 28672 + roff;

// this wave stages ONLY stripe wv of step GS into slot SLOT (1 DMA inst)
#define STAGE1(GS, SLOT)                                                      \
  {                                                                           \
    const char* gp_ = w2b + (size_t)(GS) * 4096 + (wv << 10) + lane * 16;     \
    char* lp_ = ring + (SLOT) * 4096 + (wv << 10);                            \
    GLOAD_LDS(gp_, lp_);                                                      \
  }

#define RD4(DST, SP)                                                          \
  DST[0] = *reinterpret_cast<const half8*>(SP);                               \
  DST[1] = *reinterpret_cast<const half8*>(SP + 1024);                        \
  DST[2] = *reinterpret_cast<const half8*>(SP + 2048);                        \
  DST[3] = *reinterpret_cast<const half8*>(SP + 3072);

// GROUP over steps n,n+1: consume U-pair (=B(n),B(n+1)); read V-pair <-
// slots for B(n+2),B(n+3); stage steps n+6,n+7 (clamped; tail duplicates
// land in slots never read again). 16 MFMAs over both steps.
#define GROUP(SA, SBs, UA, UB, VA, VB, SPR1, SPR2, STS1, STS2, GS1, GS2)      \
  {                                                                           \
    asm volatile("s_waitcnt vmcnt(2)" ::: "memory");                          \
    asm volatile("s_barrier" ::: "memory");                                   \
    RD4(VA, SPR1);                                                            \
    RD4(VB, SPR2);                                                            \
    int g1_ = (GS1) > 255 ? 255 : (GS1);                                      \
    int g2_ = (GS2) > 255 ? 255 : (GS2);                                      \
    STAGE1(g1_, STS1);                                                        \
    STAGE1(g2_, STS2);                                                        \
    __builtin_amdgcn_sched_barrier(0);                                        \
    __builtin_amdgcn_s_setprio(1);                                            \
    _Pragma("unroll") for (int t = 0; t < 2; ++t) {                           \
      half8 as = afr[t][SA] * hb[t];                                          \
      acc[t][0] = __builtin_amdgcn_mfma_f32_16x16x32_f16(as, UA[0], acc[t][0], 0, 0, 0); \
      acc[t][1] = __builtin_amdgcn_mfma_f32_16x16x32_f16(as, UA[1], acc[t][1], 0, 0, 0); \
      acc[t][2] = __builtin_amdgcn_mfma_f32_16x16x32_f16(as, UA[2], acc[t][2], 0, 0, 0); \
      acc[t][3] = __builtin_amdgcn_mfma_f32_16x16x32_f16(as, UA[3], acc[t][3], 0, 0, 0); \
    }                                                                         \
    _Pragma("unroll") for (int t = 0; t < 2; ++t) {                           \
      half8 as = afr[t][SBs] * hb[t];                                         \
      acc[t][0] = __builtin_amdgcn_mfma_f32_16x16x32_f16(as, UB[0], acc[t][0], 0, 0, 0); \
      acc[t][1] = __builtin_amdgcn_mfma_f32_16x16x32_f16(as, UB[1], acc[t][1], 0, 0, 0); \
      acc[t][2] = __builtin_amdgcn_mfma_f32_16x16x32_f16(as, UB[2], acc[t][2], 0, 0, 0); \
      acc[t][3] = __builtin_amdgcn_mfma_f32_16x16x32_f16(as, UB[3], acc[t][3], 0, 0, 0); \
    }                                                                         \
    __builtin_amdgcn_s_setprio(0);                                            \
  }

#define BUILD_HB(HSRC)                                                        \
  _Pragma("unroll") for (int t = 0; t < 2; ++t) {                             \
    _Float16 hf = (HSRC)[t];                                                  \
    hb[t] = (half8){hf, hf, hf, hf, hf, hf, hf, hf};                          \
  }

  // drain ALL prologue vmem (h gather, afr) so loop vmcnt counts only DMAs
  asm volatile("s_waitcnt vmcnt(0)" ::: "memory");

  // prologue: stage steps 0..5 into slots 0..5 (1 stripe per wave each)
  STAGE1(0, 0);
  STAGE1(1, 1);
  STAGE1(2, 2);
  STAGE1(3, 3);
  STAGE1(4, 4);
  STAGE1(5, 5);
  asm volatile("s_waitcnt vmcnt(4)" ::: "memory");  // own stages 0,1 landed
  asm volatile("s_barrier" ::: "memory");           // all stripes of 0,1
  half8 PA[4], PB[4], QA[4], QB[4];
  RD4(PA, sp0);  // B(0)
  RD4(PB, sp1);  // B(1)

  half2v hv = *reinterpret_cast<const half2v*>(h16w + l15 * 2);  // i = 0
  half2v hvn;

  // main loop: 32 iterations x 2 i's = 4 groups (8 steps, slots static).
  // Invariant entering ip (n = 8ip): P-pair = B(n), B(n+1).
  for (int ip = 0; ip < 32; ++ip) {
    int n = ip * 8;
    half8 hb[2];
    BUILD_HB(hv);  // i = 2ip (steps n..n+3)
    GROUP(0, 1, PA, PB, QA, QB, sp2, sp3, 6, 7, n + 6, n + 7);
    hvn = *reinterpret_cast<const half2v*>(h16w + (2 * ip + 1) * 32 + l15 * 2);
    GROUP(2, 3, QA, QB, PA, PB, sp4, sp5, 0, 1, n + 8, n + 9);
    BUILD_HB(hvn);  // i = 2ip+1 (steps n+4..n+7)
    GROUP(0, 1, PA, PB, QA, QB, sp6, sp7, 2, 3, n + 10, n + 11);
    {
      int inx = (ip < 31) ? (2 * ip + 2) : 63;
      hv = *reinterpret_cast<const half2v*>(h16w + inx * 32 + l15 * 2);
    }
    GROUP(2, 3, QA, QB, PA, PB, sp0, sp1, 4, 5, n + 12, n + 13);
  }

  // drain leftover tail DMAs
  asm volatile("s_waitcnt vmcnt(0)" ::: "memory");

  // be2 contribution (exact 0 here, kept for generality): each wave owns its
  // edges' full i-range -> add sum_i h[e,i]*be2[i*64+o] once per edge row.
  {
#pragma unroll
    for (int s = 0; s < 2; ++s) {
      half8 b2f[4];
#pragma unroll
      for (int c = 0; c < 4; ++c) {
        half8 v;
#pragma unroll
        for (int j = 0; j < 8; ++j)
          v[j] = (_Float16)be2[(s * 32 + quad * 8 + j) * 64 + c * 16 + l15];
        b2f[c] = v;
      }
#pragma unroll
      for (int t = 0; t < 2; ++t) {
        half8 ha;
#pragma unroll
        for (int j = 0; j < 8; ++j)
          ha[j] = h16w[(s * 32 + quad * 8 + j) * 32 + l15 * 2 + t];
#pragma unroll
        for (int c = 0; c < 4; ++c)
          acc[t][c] = __builtin_amdgcn_mfma_f32_16x16x32_f16(ha, b2f[c], acc[t][c], 0, 0, 0);
      }
    }
  }

  // direct scatter (no reduce): C/D layout col=lane&15, row=quad*4+reg
#pragma unroll
  for (int t = 0; t < 2; ++t) {
    int rb = wv * 32 + t * 16 + quad * 4;
#pragma unroll
    for (int c = 0; c < 4; ++c) {
      int col = c * 16 + l15;
#pragma unroll
      for (int r = 0; r < 4; ++r) {
        int d = s_dst[rb + r];
        if (d >= 0) atomicAdd(&agg[(size_t)d * OUTD + col], acc[t][c][r]);
      }
    }
  }
}

// h_out = relu(agg + bias); re-zero agg; last step also writes fp32 d_out
__global__ void update_kernel(float* __restrict__ agg,
                              const float* __restrict__ bias,
                              float* __restrict__ hout,
                              float* __restrict__ dout, int last) {
  int g = blockIdx.x * 256 + threadIdx.x;
  if (g >= Vn * OUTD) return;
  float v = agg[g];
  agg[g] = 0.0f;
  float r = fmaxf(v + bias[g & 63], 0.0f);
  hout[g] = r;
  if (last) dout[g] = r;
}

extern "C" void kernel_launch(void* const* d_in, const int* in_sizes, int n_in,
                              void* d_out, int out_size, void* d_ws, size_t ws_size,
                              hipStream_t stream) {
  const float* node = (const float*)d_in[0];
  const float* edge = (const float*)d_in[1];
  const int* src = (const int*)d_in[2];
  const int* dst = (const int*)d_in[3];
  const float* Wp   = (const float*)d_in[4];
  const float* bp   = (const float*)d_in[5];
  const float* We1  = (const float*)d_in[6];
  const float* be1  = (const float*)d_in[7];
  const float* We2  = (const float*)d_in[8];
  const float* be2  = (const float*)d_in[9];
  const float* bias = (const float*)d_in[10];
  float* out = (float*)d_out;

  char* ws = (char*)d_ws;
  float* agg = (float*)(ws);                        // 6,400,000 B
  float* h_a = (float*)(ws + 6400000);              // 6,400,000 B
  float* h_b = (float*)(ws + 12800000);             // 6,400,000 B
  _Float16* f   = (_Float16*)(ws + 19200000);       // 25,600,000 B
  _Float16* w2s = (_Float16*)(ws + 44800000);       // 1,048,576 B

  hipMemsetAsync(agg, 0, (size_t)Vn * OUTD * sizeof(float), stream);
  proj_kernel<<<Vn, 64, 0, stream>>>(node, Wp, bp, h_a);
  edge_kernel<<<En, 128, 0, stream>>>(edge, We1, be1, f);
  w2r_kernel<<<(OUTD * OUTD * EHID) / 256, 256, 0, stream>>>(We2, w2s);

  float* hin = h_a;
  float* hout = h_b;
  const int nblocks = (En + 127) / 128;  // 782
  for (int s = 0; s < NUM_STEPS; ++s) {
    msg_kernel<<<nblocks, 256, 0, stream>>>(hin, f, w2s, src, dst, be2, agg);
    update_kernel<<<(Vn * OUTD + 255) / 256, 256, 0, stream>>>(
        agg, bias, hout, out, s == NUM_STEPS - 1);
    float* t = hin; hin = hout; hout = t;
  }
}

// Round 15
// 820.025 us; speedup vs baseline: 1.1505x; 1.1505x over previous
//
#include <hip/hip_runtime.h>
#include <hip/hip_bf16.h>

#define Vn 25000
#define En 100000
#define NODE_IN 74
#define EDGE_IN 12
#define OUTD 64
#define EHID 128
#define NUM_STEPS 6

typedef __attribute__((ext_vector_type(8))) _Float16 half8;
typedef __attribute__((ext_vector_type(2))) _Float16 half2v;
typedef __attribute__((ext_vector_type(4))) float floatx4;

// h[v,o] = relu(node[v,:] @ Wp + bp)   [V,74]@[74,64]  (all fp32)
__global__ void proj_kernel(const float* __restrict__ node,
                            const float* __restrict__ Wp,
                            const float* __restrict__ bp,
                            float* __restrict__ h) {
  __shared__ float nf[NODE_IN];
  int v = blockIdx.x;
  int o = threadIdx.x;  // 64
  for (int i = o; i < NODE_IN; i += 64) nf[i] = node[(size_t)v * NODE_IN + i];
  __syncthreads();
  float acc = bp[o];
  for (int i = 0; i < NODE_IN; ++i) acc = fmaf(nf[i], Wp[i * OUTD + o], acc);
  h[(size_t)v * OUTD + o] = fmaxf(acc, 0.0f);
}

// f[e,k] = relu(edge[e,:] @ We1 + be1)   [E,12]@[12,128] fp32, stored f16
__global__ void edge_kernel(const float* __restrict__ ef,
                            const float* __restrict__ We1,
                            const float* __restrict__ be1,
                            _Float16* __restrict__ f) {
  __shared__ float es[EDGE_IN];
  int e = blockIdx.x;
  int k = threadIdx.x;  // 128
  if (k < EDGE_IN) es[k] = ef[(size_t)e * EDGE_IN + k];
  __syncthreads();
  float acc = be1[k];
  for (int j = 0; j < EDGE_IN; ++j) acc = fmaf(es[j], We1[j * EHID + k], acc);
  f[(size_t)e * EHID + k] = (_Float16)fmaxf(acc, 0.0f);
}

// SSTEP-contiguous + bank-swizzled B layout (f16) — unchanged from r7.
// Logical index: g = step*2048 + c*512 + l15*32 + quad*8 + j, step = i*4+s,
// value = f16(We2[k = s*32+quad*8+j][col = i*64 + c*16 + l15]).
// Stored at step*2048 + (eidx ^ ((eidx>>6 & 3) << 3))  (quad ^= l15[2:1]).
__global__ void w2r_kernel(const float* __restrict__ We2,
                           _Float16* __restrict__ w2s) {
  int g = blockIdx.x * 256 + threadIdx.x;  // < 524288 (logical index)
  int j = g & 7;
  int quad = (g >> 3) & 3;
  int l15 = (g >> 5) & 15;
  int c = (g >> 9) & 3;
  int step = g >> 11;     // 0..255
  int s = step & 3;
  int i = step >> 2;
  int k = s * 32 + quad * 8 + j;
  int col = i * 64 + c * 16 + l15;
  int eidx = g & 2047;
  int estore = eidx ^ (((eidx >> 6) & 3) << 3);
  w2s[((size_t)step << 11) | estore] = (_Float16)We2[(size_t)k * (OUTD * OUTD) + col];
}

#define GLOAD_LDS(gp, lp)                                                     \
  __builtin_amdgcn_global_load_lds(                                           \
      (const __attribute__((address_space(1))) void*)(gp),                    \
      (__attribute__((address_space(3))) void*)(lp), 16, 0, 0)

// Fused per-step message kernel: BLOCK-SHARED B ring, edge-split waves.
// (r12 structure, re-occupied: launch_bounds(256,4) -> 4 blocks/CU.)
// Block = 128 edges; wave wv owns edges [32wv, 32wv+32) over the FULL
// K = 8192 (no cross-wave reduce). All 4 waves traverse the same 256-step
// B sequence from ONE shared 4-slot ring: wave wv stages only stripe wv
// (1 DMA/KSTEP), all waves consume all 4 stripes. Per KSTEP: vmcnt(2)
// (own stripe of step n landed, in-order retirement, dist-3) -> raw
// s_barrier (no counter drain) -> ds_read slot n -> stage step n+3 ->
// 8 MFMA. Overwrite safety: each wave's reads of step n-1 are
// register-consumed by its MFMAs (compiler lgkm wait) BEFORE it reaches
// barrier n, so post-barrier stages can't race them.
// Occupancy math (r14 post-mortem): wave needs ~52 arch VGPR + 32 AGPR
// = 84 unified <= 128 cap @ 4 waves/SIMD; LDS 33.3KB x 4 = 133KB <= 160KB.
// r12's (256,3) was the only thing pinning us at 3 blocks/CU.
__global__ __launch_bounds__(256, 4) void msg_kernel(
    const float* __restrict__ h,
    const _Float16* __restrict__ f,
    const _Float16* __restrict__ w2s,
    const int* __restrict__ src,
    const int* __restrict__ dst,
    const float* __restrict__ be2,
    float* __restrict__ agg) {
  // [0,16384): per-wave h16 regions (4KB each): [64 i][32 pe] f16,
  //            pe(e) = (e&15)*2 + (e>>4)  -> reader's (t=0,1) pair is one b32.
  // [16384,32768): shared 4-slot B ring (4KB slots).
  __shared__ __align__(16) char smem_raw[32768];
  __shared__ int s_dst[128];

  const int tid = threadIdx.x;
  const int wv = tid >> 6;
  const int lane = tid & 63;
  const int quad = lane >> 4;
  const int l15 = lane & 15;
  const int e0 = blockIdx.x * 128;
  const int ew0 = e0 + wv * 32;   // this wave's first edge

  _Float16* h16w = (_Float16*)(smem_raw + wv * 4096);
  char* ring = smem_raw + 16384;

  // dst (wave-local 32 entries)
  if (lane < 32) {
    int eg = ew0 + lane;
    s_dst[wv * 32 + lane] = (eg < En) ? dst[eg] : -1;
  }
  // h gather (wave-private): lane l -> edge e_local = l&31, i-half = l>>5
  {
    int el = lane & 31;
    int ih = lane >> 5;
    int eg = ew0 + el;
    int sv = (eg < En) ? src[eg] : 0;
    const float4* hp = reinterpret_cast<const float4*>(h + (size_t)sv * OUTD + ih * 32);
    int pe = (el & 15) * 2 + (el >> 4);
#pragma unroll
    for (int c = 0; c < 8; ++c) {
      float4 v = hp[c];
      int i4 = ih * 32 + c * 4;
      h16w[(i4 + 0) * 32 + pe] = (_Float16)v.x;
      h16w[(i4 + 1) * 32 + pe] = (_Float16)v.y;
      h16w[(i4 + 2) * 32 + pe] = (_Float16)v.z;
      h16w[(i4 + 3) * 32 + pe] = (_Float16)v.w;
    }
  }

  // A-fragments: F rows for this wave's 2 row-tiles x 4 K-steps.
  half8 afr[2][4];
#pragma unroll
  for (int t = 0; t < 2; ++t) {
    int e = ew0 + t * 16 + l15;
    if (e >= En) e = En - 1;  // clamped rows suppressed at scatter
    const _Float16* fr = f + (size_t)e * EHID + quad * 8;
#pragma unroll
    for (int s = 0; s < 4; ++s)
      afr[t][s] = *reinterpret_cast<const half8*>(fr + s * 32);
  }

  floatx4 acc[2][4];  // [row-tile t][col-stripe c] — full K sum
  const floatx4 zero4 = (floatx4){0.f, 0.f, 0.f, 0.f};
#pragma unroll
  for (int t = 0; t < 2; ++t)
#pragma unroll
    for (int c = 0; c < 4; ++c) acc[t][c] = zero4;

  const char* w2b = (const char*)w2s;
  // swizzled per-lane byte offset within a 4KB chunk (stripe c adds 1024)
  const int roff = l15 * 64 + ((quad ^ ((l15 >> 1) & 3)) << 4);
  const char* sp0 = ring + roff;
  const char* sp1 = ring + 4096 + roff;
  const char* sp2 = ring + 8192 + roff;
  const char* sp3 = ring + 12288 + roff;

// this wave stages ONLY stripe wv of step GS into slot SLOT (1 DMA inst)
#define STAGE1(GS, SLOT)                                                      \
  {                                                                           \
    const char* gp_ = w2b + (size_t)(GS) * 4096 + (wv << 10) + lane * 16;     \
    char* lp_ = ring + (SLOT) * 4096 + (wv << 10);                            \
    GLOAD_LDS(gp_, lp_);                                                      \
  }

  // drain ALL prologue vmem (h gather, afr) so loop vmcnt counts only DMAs
  asm volatile("s_waitcnt vmcnt(0)" ::: "memory");

  // prologue: stage steps 0..2 into slots 0..2 (1 stripe per wave each)
  STAGE1(0, 0);
  STAGE1(1, 1);
  STAGE1(2, 2);

  half2v hv = *reinterpret_cast<const half2v*>(h16w + l15 * 2);  // i = 0
  half2v hvn;

// KSTEP n (static SS = n&3): vmcnt(2) drains this wave's stripe of step n
// (issued at n-3; outstanding n-2,n-1 remain); barrier => ALL stripes of
// step n landed and all waves' reads of step n-1 retired; read slot SS;
// stage step n+3 (clamped; tail duplicates land in never-again-read slots)
// into slot (SS+3)&3; 8 MFMA on the fresh reads (compiler lgkm wait).
#define KSTEP(SS, SPS, GST)                                                   \
  {                                                                           \
    asm volatile("s_waitcnt vmcnt(2)" ::: "memory");                          \
    asm volatile("s_barrier" ::: "memory");                                   \
    half8 B0 = *reinterpret_cast<const half8*>(SPS);                          \
    half8 B1 = *reinterpret_cast<const half8*>(SPS + 1024);                   \
    half8 B2 = *reinterpret_cast<const half8*>(SPS + 2048);                   \
    half8 B3 = *reinterpret_cast<const half8*>(SPS + 3072);                   \
    int gs_ = (GST) > 255 ? 255 : (GST);                                      \
    STAGE1(gs_, ((SS) + 3) & 3);                                              \
    __builtin_amdgcn_s_setprio(1);                                            \
    _Pragma("unroll") for (int t = 0; t < 2; ++t) {                           \
      half8 as = afr[t][SS] * hb[t];                                          \
      acc[t][0] = __builtin_amdgcn_mfma_f32_16x16x32_f16(as, B0, acc[t][0], 0, 0, 0); \
      acc[t][1] = __builtin_amdgcn_mfma_f32_16x16x32_f16(as, B1, acc[t][1], 0, 0, 0); \
      acc[t][2] = __builtin_amdgcn_mfma_f32_16x16x32_f16(as, B2, acc[t][2], 0, 0, 0); \
      acc[t][3] = __builtin_amdgcn_mfma_f32_16x16x32_f16(as, B3, acc[t][3], 0, 0, 0); \
    }                                                                         \
    __builtin_amdgcn_s_setprio(0);                                            \
  }

  for (int i = 0; i < 64; ++i) {
    half8 hb[2];
#pragma unroll
    for (int t = 0; t < 2; ++t) {
      _Float16 hf = hv[t];
      hb[t] = (half8){hf, hf, hf, hf, hf, hf, hf, hf};
    }
    int gs = i * 4;
    KSTEP(0, sp0, gs + 3);
    {  // prefetch next i's h pair (wave-local; compiler orders via lgkm)
      int inx = (i < 63) ? i + 1 : 63;
      hvn = *reinterpret_cast<const half2v*>(h16w + inx * 32 + l15 * 2);
    }
    KSTEP(1, sp1, gs + 4);
    KSTEP(2, sp2, gs + 5);
    KSTEP(3, sp3, gs + 6);
    hv = hvn;
  }

  // drain leftover tail DMAs before kernel teardown
  asm volatile("s_waitcnt vmcnt(0)" ::: "memory");

  // be2 contribution (exact 0 here, kept for generality): each wave owns its
  // edges' full i-range -> add sum_i h[e,i]*be2[i*64+o] once per edge row.
  {
#pragma unroll
    for (int s = 0; s < 2; ++s) {
      half8 b2f[4];
#pragma unroll
      for (int c = 0; c < 4; ++c) {
        half8 v;
#pragma unroll
        for (int j = 0; j < 8; ++j)
          v[j] = (_Float16)be2[(s * 32 + quad * 8 + j) * 64 + c * 16 + l15];
        b2f[c] = v;
      }
#pragma unroll
      for (int t = 0; t < 2; ++t) {
        half8 ha;
#pragma unroll
        for (int j = 0; j < 8; ++j)
          ha[j] = h16w[(s * 32 + quad * 8 + j) * 32 + l15 * 2 + t];
#pragma unroll
        for (int c = 0; c < 4; ++c)
          acc[t][c] = __builtin_amdgcn_mfma_f32_16x16x32_f16(ha, b2f[c], acc[t][c], 0, 0, 0);
      }
    }
  }

  // direct scatter (no reduce): C/D layout col=lane&15, row=quad*4+reg
#pragma unroll
  for (int t = 0; t < 2; ++t) {
    int rb = wv * 32 + t * 16 + quad * 4;
#pragma unroll
    for (int c = 0; c < 4; ++c) {
      int col = c * 16 + l15;
#pragma unroll
      for (int r = 0; r < 4; ++r) {
        int d = s_dst[rb + r];
        if (d >= 0) atomicAdd(&agg[(size_t)d * OUTD + col], acc[t][c][r]);
      }
    }
  }
}

// h_out = relu(agg + bias); re-zero agg; last step also writes fp32 d_out
__global__ void update_kernel(float* __restrict__ agg,
                              const float* __restrict__ bias,
                              float* __restrict__ hout,
                              float* __restrict__ dout, int last) {
  int g = blockIdx.x * 256 + threadIdx.x;
  if (g >= Vn * OUTD) return;
  float v = agg[g];
  agg[g] = 0.0f;
  float r = fmaxf(v + bias[g & 63], 0.0f);
  hout[g] = r;
  if (last) dout[g] = r;
}

extern "C" void kernel_launch(void* const* d_in, const int* in_sizes, int n_in,
                              void* d_out, int out_size, void* d_ws, size_t ws_size,
                              hipStream_t stream) {
  const float* node = (const float*)d_in[0];
  const float* edge = (const float*)d_in[1];
  const int* src = (const int*)d_in[2];
  const int* dst = (const int*)d_in[3];
  const float* Wp   = (const float*)d_in[4];
  const float* bp   = (const float*)d_in[5];
  const float* We1  = (const float*)d_in[6];
  const float* be1  = (const float*)d_in[7];
  const float* We2  = (const float*)d_in[8];
  const float* be2  = (const float*)d_in[9];
  const float* bias = (const float*)d_in[10];
  float* out = (float*)d_out;

  char* ws = (char*)d_ws;
  float* agg = (float*)(ws);                        // 6,400,000 B
  float* h_a = (float*)(ws + 6400000);              // 6,400,000 B
  float* h_b = (float*)(ws + 12800000);             // 6,400,000 B
  _Float16* f   = (_Float16*)(ws + 19200000);       // 25,600,000 B
  _Float16* w2s = (_Float16*)(ws + 44800000);       // 1,048,576 B

  hipMemsetAsync(agg, 0, (size_t)Vn * OUTD * sizeof(float), stream);
  proj_kernel<<<Vn, 64, 0, stream>>>(node, Wp, bp, h_a);
  edge_kernel<<<En, 128, 0, stream>>>(edge, We1, be1, f);
  w2r_kernel<<<(OUTD * OUTD * EHID) / 256, 256, 0, stream>>>(We2, w2s);

  float* hin = h_a;
  float* hout = h_b;
  const int nblocks = (En + 127) / 128;  // 782
  for (int s = 0; s < NUM_STEPS; ++s) {
    msg_kernel<<<nblocks, 256, 0, stream>>>(hin, f, w2s, src, dst, be2, agg);
    update_kernel<<<(Vn * OUTD + 255) / 256, 256, 0, stream>>>(
        agg, bias, hout, out, s == NUM_STEPS - 1);
    float* t = hin; hin = hout; hout = t;
  }
}